// Round 1
// baseline (335.575 us; speedup 1.0000x reference)
//
#include <hip/hip_runtime.h>
#include <math.h>

// GRU cell, fused single pass.
// B = 4194304 rows, DX = 10, DH = 4, fp32 in/out.
// Memory-bound: 72 B/row compulsory traffic -> ~48 us floor at 6.3 TB/s.
//
// Decomposition: one thread per (row, j) output element (j = tid & 3).
//  - per-thread weight set is only the j-th rows of the 6 weight matrices
//    (42 floats + biases) -> ~85 VGPRs instead of ~200 for a full-row thread.
//  - out[row*4+j] == out[linear thread index] -> perfectly coalesced stores.
//  - weight loads are wave-quad same-address -> TA-coalesced, L1-resident,
//    amortized over the grid-stride loop.

constexpr int DXc = 10;
constexpr int DHc = 4;

__global__ __launch_bounds__(256, 4)
void gru_fused(const float* __restrict__ x,
               const float* __restrict__ hidden,
               const float* __restrict__ Wzh, const float* __restrict__ bzh,
               const float* __restrict__ Wzx, const float* __restrict__ bzx,
               const float* __restrict__ Wrh, const float* __restrict__ brh,
               const float* __restrict__ Wrx, const float* __restrict__ brx,
               const float* __restrict__ Wnx, const float* __restrict__ bnx,
               const float* __restrict__ Wnh, const float* __restrict__ bnh,
               float* __restrict__ out, int total /* = B*DH */)
{
    const int tid = blockIdx.x * blockDim.x + threadIdx.x;
    const int nth = gridDim.x * blockDim.x;   // multiple of 4 -> j invariant
    const int j   = tid & 3;                  // which of the 4 output units

    // j-th weight rows into registers (uniform-per-quad, L1-served, once).
    float wzh[DHc], wrh[DHc], wnh[DHc];
    float wzx[DXc], wrx[DXc], wnx[DXc];
#pragma unroll
    for (int k = 0; k < DHc; ++k) {
        wzh[k] = Wzh[j * DHc + k];
        wrh[k] = Wrh[j * DHc + k];
        wnh[k] = Wnh[j * DHc + k];
    }
#pragma unroll
    for (int k = 0; k < DXc; ++k) {
        wzx[k] = Wzx[j * DXc + k];
        wrx[k] = Wrx[j * DXc + k];
        wnx[k] = Wnx[j * DXc + k];
    }
    const float bz    = bzh[j] + bzx[j];   // combined z bias
    const float br    = brh[j] + brx[j];   // combined r bias
    const float bnh_j = bnh[j];            // stays inside r*(...) term
    const float bnx_j = bnx[j];

    for (int p = tid; p < total; p += nth) {
        const int row = p >> 2;

        // x row: 10 floats = 5 x float2 (row*40 B base -> 8 B aligned).
        const float2* xr = reinterpret_cast<const float2*>(x + row * DXc);
        float xv[DXc];
#pragma unroll
        for (int q = 0; q < DXc / 2; ++q) {
            const float2 t = xr[q];
            xv[2 * q]     = t.x;
            xv[2 * q + 1] = t.y;
        }
        // hidden row: one aligned float4.
        const float4 hv = *reinterpret_cast<const float4*>(hidden + row * DHc);
        const float hvv[DHc] = {hv.x, hv.y, hv.z, hv.w};  // compile-time idx only

        float az = bz, ar = br, ah = bnh_j, ax = bnx_j;
#pragma unroll
        for (int k = 0; k < DHc; ++k) {
            az = fmaf(hvv[k], wzh[k], az);
            ar = fmaf(hvv[k], wrh[k], ar);
            ah = fmaf(hvv[k], wnh[k], ah);
        }
#pragma unroll
        for (int k = 0; k < DXc; ++k) {
            az = fmaf(xv[k], wzx[k], az);
            ar = fmaf(xv[k], wrx[k], ar);
            ax = fmaf(xv[k], wnx[k], ax);
        }

        const float z = 1.0f / (1.0f + expf(-az));
        const float r = 1.0f / (1.0f + expf(-ar));
        const float n = tanhf(fmaf(r, ah, ax));

        // hidden component j for the blend (runtime j -> cndmask chain, no scratch)
        const float hj = (j < 2) ? (j == 0 ? hv.x : hv.y)
                                 : (j == 2 ? hv.z : hv.w);

        out[p] = fmaf(z, hj - n, n);   // (1-z)*n + z*h == n + z*(h-n)
    }
}

extern "C" void kernel_launch(void* const* d_in, const int* in_sizes, int n_in,
                              void* d_out, int out_size, void* d_ws, size_t ws_size,
                              hipStream_t stream) {
    const float* x   = (const float*)d_in[0];
    const float* h   = (const float*)d_in[1];
    const float* Wzh = (const float*)d_in[2];
    const float* bzh = (const float*)d_in[3];
    const float* Wzx = (const float*)d_in[4];
    const float* bzx = (const float*)d_in[5];
    const float* Wrh = (const float*)d_in[6];
    const float* brh = (const float*)d_in[7];
    const float* Wrx = (const float*)d_in[8];
    const float* brx = (const float*)d_in[9];
    const float* Wnx = (const float*)d_in[10];
    const float* bnx = (const float*)d_in[11];
    const float* Wnh = (const float*)d_in[12];
    const float* bnh = (const float*)d_in[13];
    float* out = (float*)d_out;

    const int total = out_size;  // B * DH = 16,777,216
    const int block = 256;
    const int grid  = 2048;      // 524288 threads -> 32 grid-stride iters

    gru_fused<<<grid, block, 0, stream>>>(x, h, Wzh, bzh, Wzx, bzx,
                                          Wrh, brh, Wrx, brx,
                                          Wnx, bnx, Wnh, bnh, out, total);
}

// Round 2
// 326.542 us; speedup vs baseline: 1.0277x; 1.0277x over previous
//
#include <hip/hip_runtime.h>
#include <math.h>

// GRU cell, fused single pass. B = 4,194,304 rows, DX = 10, DH = 4, fp32.
// Compulsory traffic ~302 MB logical (~185 MB DRAM after L3) -> ~30-48 us floor.
//
// R1 changes vs R0 (which ran 119 us, VALUBusy 50%, HBM 19%):
//  - j (output unit) is now WAVE-UNIFORM: wave w of each 4-wave block computes
//    unit w for 64 rows (lane = row). All 46 weight/bias values are forced into
//    SGPRs via readfirstlane -> loaded once, zero VGPR pressure, no per-iter
//    reloads (R0's VGPR_Count=36 proved weights were being re-fetched in-loop).
//  - fast transcendentals: __expf (v_exp_f32) + __builtin_amdgcn_rcpf replace
//    ocml expf/tanhf/div (~50 VALU saved per element; error ~1e-6 vs 7.8e-3 slack).
//  - stores: wave-uniform j makes out[row*4+j] stride-16B, so outputs bounce
//    through a 2 KB double-buffered LDS transpose (swizzled, <=2-way banks =
//    free) -> fully coalesced 256-dword block stores.

constexpr int DXc = 10;
constexpr int DHc = 4;

__device__ __forceinline__ float sgpr_f(float v) {
    // Force a wave-uniform value into an SGPR (and keep it there).
    return __uint_as_float(__builtin_amdgcn_readfirstlane(__float_as_uint(v)));
}

__global__ __launch_bounds__(256, 8)
void gru_fused(const float* __restrict__ x,
               const float* __restrict__ hidden,
               const float* __restrict__ Wzh, const float* __restrict__ bzh,
               const float* __restrict__ Wzx, const float* __restrict__ bzx,
               const float* __restrict__ Wrh, const float* __restrict__ brh,
               const float* __restrict__ Wrx, const float* __restrict__ brx,
               const float* __restrict__ Wnx, const float* __restrict__ bnx,
               const float* __restrict__ Wnh, const float* __restrict__ bnh,
               float* __restrict__ out, int nrows)
{
    __shared__ float obuf[2 * 256];   // double-buffered [row][j] transpose tile

    const int tid  = threadIdx.x;
    const int lane = tid & 63;
    const int j    = __builtin_amdgcn_readfirstlane(tid >> 6);  // unit 0..3, wave-uniform

    // ---- weights -> SGPRs (once) ----
    float wzh[DHc], wrh[DHc], wnh[DHc];
    float wzx[DXc], wrx[DXc], wnx[DXc];
#pragma unroll
    for (int k = 0; k < DHc; ++k) {
        wzh[k] = sgpr_f(Wzh[j * DHc + k]);
        wrh[k] = sgpr_f(Wrh[j * DHc + k]);
        wnh[k] = sgpr_f(Wnh[j * DHc + k]);
    }
#pragma unroll
    for (int k = 0; k < DXc; ++k) {
        wzx[k] = sgpr_f(Wzx[j * DXc + k]);
        wrx[k] = sgpr_f(Wrx[j * DXc + k]);
        wnx[k] = sgpr_f(Wnx[j * DXc + k]);
    }
    const float bz    = sgpr_f(bzh[j] + bzx[j]);
    const float br    = sgpr_f(brh[j] + brx[j]);
    const float bnh_j = sgpr_f(bnh[j]);
    const float bnx_j = sgpr_f(bnx[j]);

    // ---- LDS transpose indices (hoisted; swizzle keeps banks <=2-way) ----
    // write: logical (lane,j) -> phys lane*4 + ((j + (lane>>3)) & 3)
    // read : thread t wants logical t -> phys (t&~3) | (((t&3) + (t>>5)) & 3)
    int widx = (lane << 2) | ((j + (lane >> 3)) & 3);
    int ridx = (tid & ~3) | (((tid & 3) + (tid >> 5)) & 3);

    const int rstride = gridDim.x * 64;
    for (int row0 = blockIdx.x * 64; row0 < nrows; row0 += rstride) {
        const int row = row0 + lane;

        // x row: 10 floats = 5 x float2 (8 B aligned); hidden row: float4.
        const float2* xr = reinterpret_cast<const float2*>(x + row * DXc);
        const float2 x0 = xr[0], x1 = xr[1], x2 = xr[2], x3 = xr[3], x4 = xr[4];
        const float4 hv = *reinterpret_cast<const float4*>(hidden + row * DHc);
        const float xv[DXc]  = {x0.x, x0.y, x1.x, x1.y, x2.x,
                                x2.y, x3.x, x3.y, x4.x, x4.y};
        const float hvv[DHc] = {hv.x, hv.y, hv.z, hv.w};

        float az = bz, ar = br, ah = bnh_j, ax = bnx_j;
#pragma unroll
        for (int k = 0; k < DHc; ++k) {            // SGPR-operand FMAs
            az = fmaf(hvv[k], wzh[k], az);
            ar = fmaf(hvv[k], wrh[k], ar);
            ah = fmaf(hvv[k], wnh[k], ah);
        }
#pragma unroll
        for (int k = 0; k < DXc; ++k) {
            az = fmaf(xv[k], wzx[k], az);
            ar = fmaf(xv[k], wrx[k], ar);
            ax = fmaf(xv[k], wnx[k], ax);
        }

        // fast sigmoid / tanh: v_exp_f32 + v_rcp_f32 (err ~1e-6)
        const float z = __builtin_amdgcn_rcpf(1.0f + __expf(-az));
        const float r = __builtin_amdgcn_rcpf(1.0f + __expf(-ar));
        const float t = fmaf(r, ah, ax);
        const float n = fmaf(-2.0f, __builtin_amdgcn_rcpf(1.0f + __expf(2.0f * t)), 1.0f);

        const float hj = (j == 0) ? hv.x : (j == 1) ? hv.y : (j == 2) ? hv.z : hv.w;
        const float o  = fmaf(z, hj - n, n);       // (1-z)*n + z*h

        // transpose through LDS -> coalesced store
        obuf[widx] = o;
        __syncthreads();                            // also fences prev buf reuse
        out[row0 * 4 + tid] = obuf[ridx];
        widx ^= 256;
        ridx ^= 256;
    }
}

extern "C" void kernel_launch(void* const* d_in, const int* in_sizes, int n_in,
                              void* d_out, int out_size, void* d_ws, size_t ws_size,
                              hipStream_t stream) {
    const float* x   = (const float*)d_in[0];
    const float* h   = (const float*)d_in[1];
    const float* Wzh = (const float*)d_in[2];
    const float* bzh = (const float*)d_in[3];
    const float* Wzx = (const float*)d_in[4];
    const float* bzx = (const float*)d_in[5];
    const float* Wrh = (const float*)d_in[6];
    const float* brh = (const float*)d_in[7];
    const float* Wrx = (const float*)d_in[8];
    const float* brx = (const float*)d_in[9];
    const float* Wnx = (const float*)d_in[10];
    const float* bnx = (const float*)d_in[11];
    const float* Wnh = (const float*)d_in[12];
    const float* bnh = (const float*)d_in[13];
    float* out = (float*)d_out;

    const int nrows = out_size / 4;   // 4,194,304
    const int block = 256;            // 4 waves: one per output unit
    const int grid  = 2048;           // 8 blocks/CU x 256 CUs = exact machine fill

    gru_fused<<<grid, block, 0, stream>>>(x, h, Wzh, bzh, Wzx, bzx,
                                          Wrh, brh, Wrx, brx,
                                          Wnx, bnx, Wnh, bnh, out, nrows);
}